// Round 2
// baseline (251.322 us; speedup 1.0000x reference)
//
#include <hip/hip_runtime.h>
#include <hip/hip_bf16.h>
#include <stdint.h>

// B=4, S=2048, HDIM=1024, H=16, D=64, L=128, NB=16
// GEMMs: M = B*S = 8192, N = H*D = 1024, K = HDIM = 1024
constexpr int GM = 8192;
constexpr int GK = 1024;
constexpr int GN = 1024;
constexpr size_t NACT = (size_t)GM * GN;      // 8388608 elements
constexpr int CHUNK = 32;                      // scan chunk length
constexpr int NCHUNK = 64;                     // 64*32 = 2048 = S
constexpr int NCH = 4096;                      // B*H*D channels

#define DEVINL __device__ __forceinline__

typedef __attribute__((ext_vector_type(8))) short bf16x8;
typedef __attribute__((ext_vector_type(8))) unsigned short u16x8;
typedef __attribute__((ext_vector_type(4))) float f32x4;

DEVINL float sigmoidf_(float x) { return 1.0f / (1.0f + __expf(-x)); }

DEVINL unsigned short f2bf(float x) {
  unsigned int u = __builtin_bit_cast(unsigned int, x);
  unsigned int rnd = 0x7fffu + ((u >> 16) & 1u);
  return (unsigned short)((u + rnd) >> 16);
}
DEVINL float bf2f(unsigned short u) {
  unsigned int x = ((unsigned int)u) << 16;
  return __builtin_bit_cast(float, x);
}

DEVINL void gload16(const void* g, void* l) {
  __builtin_amdgcn_global_load_lds(
      (const __attribute__((address_space(1))) unsigned int*)g,
      (__attribute__((address_space(3))) unsigned int*)l, 16, 0, 0);
}

// ---------------- prep: transpose+cvt all 5 weights in one dispatch ----------------
struct TPtrs {
  const float* src[5];
  unsigned short* dst[5];
};

__global__ void transpose_cvt_all(TPtrs p) {
  const float* __restrict__ W = p.src[blockIdx.z];
  unsigned short* __restrict__ Wt = p.dst[blockIdx.z];
  __shared__ float tile[32][33];
  int n0 = blockIdx.x * 32, k0 = blockIdx.y * 32;
  int tx = threadIdx.x & 31, ty = threadIdx.x >> 5;  // 32x8
#pragma unroll
  for (int i = 0; i < 32; i += 8)
    tile[ty + i][tx] = W[(size_t)(k0 + ty + i) * GN + n0 + tx];
  __syncthreads();
#pragma unroll
  for (int i = 0; i < 32; i += 8)
    Wt[(size_t)(n0 + ty + i) * GK + k0 + tx] = f2bf(tile[tx][ty + i]);
}

// =====================================================================
// MFMA GEMM core: 128x128 tile, BK=32, 4 waves, m97-style 2-barrier loop.
// A is f32 in HBM, converted to bf16 during reg-staging; W is bf16 [n][k].
// =====================================================================
struct GemmCtx {
  int wave, lane, bm, bn, wm, wn, lrow, lko, srow, scol8;
};

DEVINL GemmCtx make_ctx() {
  GemmCtx c;
  int tid = threadIdx.x;
  c.wave = tid >> 6;
  c.lane = tid & 63;
  c.bm = blockIdx.x;
  c.bn = blockIdx.y;
  c.wm = (c.wave >> 1) * 64;
  c.wn = (c.wave & 1) * 64;
  c.lrow = c.lane & 15;
  c.lko = (c.lane >> 4) * 8;
  c.srow = tid >> 2;          // 0..63
  c.scol8 = (tid & 3) * 8;    // bf16/f32 col offset, 8 elements
  return c;
}

// one full K loop over f32 A + bf16 W, accumulating into acc
DEVINL void gemm_kloop_f32A(const GemmCtx& c, const float* __restrict__ A,
                            const unsigned short* __restrict__ W,
                            unsigned short* As, unsigned short* Bs,
                            f32x4 (&acc)[4][4]) {
  const int wave = c.wave;
  for (int k0 = 0; k0 < GK; k0 += 32) {
    __syncthreads();  // previous tile's LDS reads done
    // issue A f32 loads early (async until first use)
    const float* a0p = A + (size_t)(c.bm * 128 + c.srow) * GK + k0 + c.scol8;
    const float* a1p = a0p + (size_t)64 * GK;
    float4 v0 = *(const float4*)(a0p);
    float4 v1 = *(const float4*)(a0p + 4);
    float4 v2 = *(const float4*)(a1p);
    float4 v3 = *(const float4*)(a1p + 4);
    // W -> LDS direct (in flight across the pack below)
    gload16(W + (size_t)(c.bn * 128 + c.srow) * GK + k0 + c.scol8,
            (char*)Bs + wave * 1024);
    gload16(W + (size_t)(c.bn * 128 + 64 + c.srow) * GK + k0 + c.scol8,
            (char*)Bs + 4096 + wave * 1024);
    // pack f32 -> bf16, write A tile
    u16x8 p0, p1;
    p0[0] = f2bf(v0.x); p0[1] = f2bf(v0.y); p0[2] = f2bf(v0.z); p0[3] = f2bf(v0.w);
    p0[4] = f2bf(v1.x); p0[5] = f2bf(v1.y); p0[6] = f2bf(v1.z); p0[7] = f2bf(v1.w);
    p1[0] = f2bf(v2.x); p1[1] = f2bf(v2.y); p1[2] = f2bf(v2.z); p1[3] = f2bf(v2.w);
    p1[4] = f2bf(v3.x); p1[5] = f2bf(v3.y); p1[6] = f2bf(v3.z); p1[7] = f2bf(v3.w);
    *(u16x8*)&As[c.srow * 32 + c.scol8] = p0;
    *(u16x8*)&As[(c.srow + 64) * 32 + c.scol8] = p1;
    __syncthreads();  // drains vmcnt (W gloads) + lgkm (A ds_writes)

    bf16x8 af[4], bfr[4];
#pragma unroll
    for (int m = 0; m < 4; ++m)
      af[m] = *(const bf16x8*)&As[(c.wm + m * 16 + c.lrow) * 32 + c.lko];
#pragma unroll
    for (int n = 0; n < 4; ++n)
      bfr[n] = *(const bf16x8*)&Bs[(c.wn + n * 16 + c.lrow) * 32 + c.lko];
#pragma unroll
    for (int m = 0; m < 4; ++m)
#pragma unroll
      for (int n = 0; n < 4; ++n)
        acc[m][n] = __builtin_amdgcn_mfma_f32_16x16x32_bf16(af[m], bfr[n],
                                                            acc[m][n], 0, 0, 0);
  }
}

// ---------------- f-gate + o-gate in one dispatch (grid.z selects) ----------------
__global__ __launch_bounds__(256) void gemm_gates_fo(
    const float* __restrict__ Aa, const unsigned short* __restrict__ Wa,
    const float* __restrict__ ba, unsigned short* __restrict__ outa,
    const float* __restrict__ Ab, const unsigned short* __restrict__ Wb,
    const float* __restrict__ bb, unsigned short* __restrict__ outb) {
  __shared__ __align__(16) unsigned short As[128 * 32];
  __shared__ __align__(16) unsigned short Bs[128 * 32];
  const bool second = blockIdx.z != 0;
  const float* A = second ? Ab : Aa;
  const unsigned short* W = second ? Wb : Wa;
  const float* bias = second ? bb : ba;
  unsigned short* out = second ? outb : outa;
  const float addc = second ? 0.0f : 1.0f;   // f-gate: sigmoid(x + b + 1)

  GemmCtx c = make_ctx();
  f32x4 acc[4][4];
#pragma unroll
  for (int m = 0; m < 4; ++m)
#pragma unroll
    for (int n = 0; n < 4; ++n) acc[m][n] = (f32x4){0.f, 0.f, 0.f, 0.f};

  gemm_kloop_f32A(c, A, W, As, Bs, acc);

  float bv[4];
#pragma unroll
  for (int n = 0; n < 4; ++n) bv[n] = bias[c.bn * 128 + c.wn + n * 16 + c.lrow];

#pragma unroll
  for (int m = 0; m < 4; ++m)
#pragma unroll
    for (int n = 0; n < 4; ++n) {
      int gc = c.bn * 128 + c.wn + n * 16 + c.lrow;
#pragma unroll
      for (int j = 0; j < 4; ++j) {
        int gr = c.bm * 128 + c.wm + m * 16 + (c.lane >> 4) * 4 + j;
        float v = acc[m][n][j] + bv[n] + addc;
        out[(size_t)gr * GN + gc] = f2bf(sigmoidf_(v));
      }
    }
}

// ---------------- u-gate: sigmoid(i)*tanh(z), two K loops ----------------
__global__ __launch_bounds__(256) void gemm_gate_u(
    const float* __restrict__ Ai, const unsigned short* __restrict__ Wi,
    const float* __restrict__ bi,
    const float* __restrict__ Az, const unsigned short* __restrict__ Wz,
    const float* __restrict__ bz, unsigned short* __restrict__ out) {
  __shared__ __align__(16) unsigned short As[128 * 32];
  __shared__ __align__(16) unsigned short Bs[128 * 32];
  GemmCtx c = make_ctx();
  f32x4 acc1[4][4], acc2[4][4];
#pragma unroll
  for (int m = 0; m < 4; ++m)
#pragma unroll
    for (int n = 0; n < 4; ++n) {
      acc1[m][n] = (f32x4){0.f, 0.f, 0.f, 0.f};
      acc2[m][n] = (f32x4){0.f, 0.f, 0.f, 0.f};
    }

  gemm_kloop_f32A(c, Ai, Wi, As, Bs, acc1);
  gemm_kloop_f32A(c, Az, Wz, As, Bs, acc2);

  float b1v[4], b2v[4];
#pragma unroll
  for (int n = 0; n < 4; ++n) {
    int gc = c.bn * 128 + c.wn + n * 16 + c.lrow;
    b1v[n] = bi[gc];
    b2v[n] = bz[gc];
  }

#pragma unroll
  for (int m = 0; m < 4; ++m)
#pragma unroll
    for (int n = 0; n < 4; ++n) {
      int gc = c.bn * 128 + c.wn + n * 16 + c.lrow;
#pragma unroll
      for (int j = 0; j < 4; ++j) {
        int gr = c.bm * 128 + c.wm + m * 16 + (c.lane >> 4) * 4 + j;
        float vi = acc1[m][n][j] + b1v[n];
        float vz = acc2[m][n][j] + b2v[n];
        out[(size_t)gr * GN + gc] = f2bf(sigmoidf_(vi) * tanhf(vz));
      }
    }
}

// ---------------- output projection: bf16 A (Hb), f32 out ----------------
__global__ __launch_bounds__(256) void gemm_proj(
    const unsigned short* __restrict__ A, const unsigned short* __restrict__ W,
    const float* __restrict__ bias, float* __restrict__ out) {
  __shared__ __align__(16) unsigned short As[128 * 32];
  __shared__ __align__(16) unsigned short Bs[128 * 32];
  GemmCtx c = make_ctx();
  const int wave = c.wave;
  f32x4 acc[4][4];
#pragma unroll
  for (int m = 0; m < 4; ++m)
#pragma unroll
    for (int n = 0; n < 4; ++n) acc[m][n] = (f32x4){0.f, 0.f, 0.f, 0.f};

  for (int k0 = 0; k0 < GK; k0 += 32) {
    __syncthreads();
    gload16(A + (size_t)(c.bm * 128 + c.srow) * GK + k0 + c.scol8,
            (char*)As + wave * 1024);
    gload16(A + (size_t)(c.bm * 128 + 64 + c.srow) * GK + k0 + c.scol8,
            (char*)As + 4096 + wave * 1024);
    gload16(W + (size_t)(c.bn * 128 + c.srow) * GK + k0 + c.scol8,
            (char*)Bs + wave * 1024);
    gload16(W + (size_t)(c.bn * 128 + 64 + c.srow) * GK + k0 + c.scol8,
            (char*)Bs + 4096 + wave * 1024);
    __syncthreads();

    bf16x8 af[4], bfr[4];
#pragma unroll
    for (int m = 0; m < 4; ++m)
      af[m] = *(const bf16x8*)&As[(c.wm + m * 16 + c.lrow) * 32 + c.lko];
#pragma unroll
    for (int n = 0; n < 4; ++n)
      bfr[n] = *(const bf16x8*)&Bs[(c.wn + n * 16 + c.lrow) * 32 + c.lko];
#pragma unroll
    for (int m = 0; m < 4; ++m)
#pragma unroll
      for (int n = 0; n < 4; ++n)
        acc[m][n] = __builtin_amdgcn_mfma_f32_16x16x32_bf16(af[m], bfr[n],
                                                            acc[m][n], 0, 0, 0);
  }

  float bv[4];
#pragma unroll
  for (int n = 0; n < 4; ++n) bv[n] = bias[c.bn * 128 + c.wn + n * 16 + c.lrow];

#pragma unroll
  for (int m = 0; m < 4; ++m)
#pragma unroll
    for (int n = 0; n < 4; ++n) {
      int gc = c.bn * 128 + c.wn + n * 16 + c.lrow;
#pragma unroll
      for (int j = 0; j < 4; ++j) {
        int gr = c.bm * 128 + c.wm + m * 16 + (c.lane >> 4) * 4 + j;
        out[(size_t)gr * GN + gc] = acc[m][n][j] + bv[n];
      }
    }
}

// ---------------- scan phase A: per-chunk (prod f, local c) ----------------
__global__ void scan_phaseA_kernel(const unsigned short* __restrict__ F,
                                   const unsigned short* __restrict__ U,
                                   float* __restrict__ Pt, float* __restrict__ Ct) {
  int tid = blockIdx.x * blockDim.x + threadIdx.x;  // NCH * NCHUNK = 262144
  int ch = tid & (NCH - 1), chunk = tid >> 12;
  int b = ch >> 10, n = ch & 1023;
  size_t base = ((size_t)(b * 2048 + chunk * CHUNK)) * 1024 + n;
  float c = 0.f, P = 1.f;
#pragma unroll 8
  for (int t = 0; t < CHUNK; ++t) {
    size_t idx = base + (size_t)t * 1024;
    float f = bf2f(F[idx]);
    float u = bf2f(U[idx]);
    c = __builtin_fmaf(f, c, u);
    P *= f;
  }
  Pt[tid] = P;
  Ct[tid] = c;
}

// ---------------- scan combine: sequential over 64 chunks ----------------
__global__ void scan_combine_kernel(const float* __restrict__ Pt,
                                    const float* __restrict__ Ct,
                                    const float* __restrict__ c0,
                                    float* __restrict__ Cin,
                                    float* __restrict__ last_c) {
  int ch = blockIdx.x * blockDim.x + threadIdx.x;  // 4096
  float c = c0[ch];
#pragma unroll
  for (int j = 0; j < NCHUNK; ++j) {
    Cin[j * NCH + ch] = c;
    c = __builtin_fmaf(Pt[j * NCH + ch], c, Ct[j * NCH + ch]);
  }
  last_c[ch] = c;
}

// ---------------- scan phase C: replay with carry, emit h ----------------
__global__ void scan_phaseC_kernel(const unsigned short* __restrict__ F,
                                   const unsigned short* __restrict__ U,
                                   const unsigned short* __restrict__ O,
                                   const float* __restrict__ Cin,
                                   unsigned short* __restrict__ Hb,
                                   float* __restrict__ last_h) {
  int tid = blockIdx.x * blockDim.x + threadIdx.x;
  int ch = tid & (NCH - 1), chunk = tid >> 12;
  int b = ch >> 10, n = ch & 1023;
  size_t base = ((size_t)(b * 2048 + chunk * CHUNK)) * 1024 + n;
  float c = Cin[tid];  // tid == chunk*NCH + ch
  float h = 0.f;
#pragma unroll 8
  for (int t = 0; t < CHUNK; ++t) {
    size_t idx = base + (size_t)t * 1024;
    float f = bf2f(F[idx]);
    float u = bf2f(U[idx]);
    float o = bf2f(O[idx]);
    c = __builtin_fmaf(f, c, u);
    h = o * tanhf(c);
    Hb[idx] = f2bf(h);
  }
  if (chunk == NCHUNK - 1) last_h[ch] = h;
}

extern "C" void kernel_launch(void* const* d_in, const int* in_sizes, int n_in,
                              void* d_out, int out_size, void* d_ws, size_t ws_size,
                              hipStream_t stream) {
  const float* f_in = (const float*)d_in[0];
  const float* i_in = (const float*)d_in[1];
  const float* z_in = (const float*)d_in[2];
  const float* o_in = (const float*)d_in[3];
  const float* c0 = (const float*)d_in[4];
  // d_in[5] = h0 (unused by reference)
  const float* Wf = (const float*)d_in[6];
  const float* bf_ = (const float*)d_in[7];
  const float* Wi = (const float*)d_in[8];
  const float* bi = (const float*)d_in[9];
  const float* Wz = (const float*)d_in[10];
  const float* bz = (const float*)d_in[11];
  const float* Wo = (const float*)d_in[12];
  const float* bo = (const float*)d_in[13];
  const float* Wp = (const float*)d_in[14];
  const float* bp = (const float*)d_in[15];

  float* y = (float*)d_out;
  float* last_c = y + NACT;
  float* last_h = last_c + NCH;

  // workspace carve
  char* w = (char*)d_ws;
  const size_t WBYTES = (size_t)GK * GN * 2;  // 2 MiB per transposed weight
  unsigned short* Wtf = (unsigned short*)(w + 0 * WBYTES);
  unsigned short* Wti = (unsigned short*)(w + 1 * WBYTES);
  unsigned short* Wtz = (unsigned short*)(w + 2 * WBYTES);
  unsigned short* Wto = (unsigned short*)(w + 3 * WBYTES);
  unsigned short* Wtp = (unsigned short*)(w + 4 * WBYTES);
  char* gp = w + 5 * WBYTES;
  const size_t ABYTES = NACT * 2;  // 16 MiB
  unsigned short* F = (unsigned short*)(gp + 0 * ABYTES);
  unsigned short* U = (unsigned short*)(gp + 1 * ABYTES);
  unsigned short* O = (unsigned short*)(gp + 2 * ABYTES);
  unsigned short* Hb = (unsigned short*)(gp + 3 * ABYTES);
  char* sp = gp + 4 * ABYTES;
  const size_t SBYTES = (size_t)NCH * NCHUNK * 4;  // 1 MiB
  float* Pt = (float*)(sp + 0 * SBYTES);
  float* Ct = (float*)(sp + 1 * SBYTES);
  float* Cin = (float*)(sp + 2 * SBYTES);

  // 1) transpose+convert all weights -> Wt[n][k] bf16 (one dispatch)
  TPtrs tp;
  tp.src[0] = Wf; tp.src[1] = Wi; tp.src[2] = Wz; tp.src[3] = Wo; tp.src[4] = Wp;
  tp.dst[0] = Wtf; tp.dst[1] = Wti; tp.dst[2] = Wtz; tp.dst[3] = Wto; tp.dst[4] = Wtp;
  transpose_cvt_all<<<dim3(32, 32, 5), 256, 0, stream>>>(tp);

  // 2) gate GEMMs (f32 A staged+converted in-kernel)
  gemm_gates_fo<<<dim3(GM / 128, GN / 128, 2), 256, 0, stream>>>(
      f_in, Wtf, bf_, F, o_in, Wto, bo, O);
  gemm_gate_u<<<dim3(GM / 128, GN / 128), 256, 0, stream>>>(
      i_in, Wti, bi, z_in, Wtz, bz, U);

  // 3) chunked linear-recurrence scan
  scan_phaseA_kernel<<<(NCH * NCHUNK) / 256, 256, 0, stream>>>(F, U, Pt, Ct);
  scan_combine_kernel<<<NCH / 256, 256, 0, stream>>>(Pt, Ct, c0, Cin, last_c);
  scan_phaseC_kernel<<<(NCH * NCHUNK) / 256, 256, 0, stream>>>(F, U, O, Cin, Hb, last_h);

  // 4) output projection
  gemm_proj<<<dim3(GM / 128, GN / 128), 256, 0, stream>>>(Hb, Wtp, bp, y);
}

// Round 3
// 217.172 us; speedup vs baseline: 1.1573x; 1.1573x over previous
//
#include <hip/hip_runtime.h>
#include <hip/hip_bf16.h>
#include <stdint.h>

// B=4, S=2048, HDIM=1024, H=16, D=64, L=128, NB=16
// GEMMs: M = B*S = 8192, N = H*D = 1024, K = HDIM = 1024
constexpr int GM = 8192;
constexpr int GK = 1024;
constexpr int GN = 1024;
constexpr size_t NACT = (size_t)GM * GN;      // 8388608 elements
constexpr int CHUNK = 32;                      // scan chunk length
constexpr int NCHUNK = 64;                     // 64*32 = 2048 = S
constexpr int NCH = 4096;                      // B*H*D channels
constexpr int NT = GK / 64;                    // 16 K-tiles of 64

#define DEVINL __device__ __forceinline__

typedef __attribute__((ext_vector_type(8))) short bf16x8;
typedef __attribute__((ext_vector_type(4))) float f32x4;

DEVINL float sigmoidf_(float x) { return 1.0f / (1.0f + __expf(-x)); }

DEVINL unsigned short f2bf(float x) {
  unsigned int u = __builtin_bit_cast(unsigned int, x);
  unsigned int rnd = 0x7fffu + ((u >> 16) & 1u);
  return (unsigned short)((u + rnd) >> 16);
}
DEVINL float bf2f(unsigned short u) {
  unsigned int x = ((unsigned int)u) << 16;
  return __builtin_bit_cast(float, x);
}

DEVINL void gload16(const void* g, void* l) {
  __builtin_amdgcn_global_load_lds(
      (const __attribute__((address_space(1))) unsigned int*)g,
      (__attribute__((address_space(3))) unsigned int*)l, 16, 0, 0);
}

// ---------------- prep: f32 -> bf16 convert, 4 arrays in one dispatch ----------------
__global__ void cvt4_kernel(const float* __restrict__ s0, const float* __restrict__ s1,
                            const float* __restrict__ s2, const float* __restrict__ s3,
                            unsigned short* __restrict__ d0, unsigned short* __restrict__ d1,
                            unsigned short* __restrict__ d2, unsigned short* __restrict__ d3,
                            int n4) {
  const float* s;
  unsigned short* d;
  switch (blockIdx.y) {
    case 0: s = s0; d = d0; break;
    case 1: s = s1; d = d1; break;
    case 2: s = s2; d = d2; break;
    default: s = s3; d = d3; break;
  }
  int stride = gridDim.x * blockDim.x;
  for (int i = blockIdx.x * blockDim.x + threadIdx.x; i < n4; i += stride) {
    float4 v = ((const float4*)s)[i];
    ushort4 o;
    o.x = f2bf(v.x); o.y = f2bf(v.y); o.z = f2bf(v.z); o.w = f2bf(v.w);
    ((ushort4*)d)[i] = o;
  }
}

// ---------------- prep: transpose+cvt all 5 weights in one dispatch ----------------
struct TPtrs {
  const float* src[5];
  unsigned short* dst[5];
};

__global__ void transpose_cvt_all(TPtrs p) {
  const float* __restrict__ W = p.src[blockIdx.z];
  unsigned short* __restrict__ Wt = p.dst[blockIdx.z];
  __shared__ float tile[32][33];
  int n0 = blockIdx.x * 32, k0 = blockIdx.y * 32;
  int tx = threadIdx.x & 31, ty = threadIdx.x >> 5;  // 32x8
#pragma unroll
  for (int i = 0; i < 32; i += 8)
    tile[ty + i][tx] = W[(size_t)(k0 + ty + i) * GN + n0 + tx];
  __syncthreads();
#pragma unroll
  for (int i = 0; i < 32; i += 8)
    Wt[(size_t)(n0 + ty + i) * GK + k0 + tx] = f2bf(tile[tx][ty + i]);
}

// =====================================================================
// 256x256 tile, BK=64, 8 waves (2M x 4N), phase-interleaved schedule.
// LDS 128 KiB: 2 dbuf x (A 32K + B 32K). A,W both bf16 row-major [.][1024].
// Staging: global_load_lds w/ linear LDS dest + inverse-XOR-swizzled global
// source; reads apply the same XOR (involution): cb ^= (row&7)<<4.
// Counted vmcnt(8): all 8 loads of tile t+1 issue at phase 1 of tile t and
// stay in flight across the whole K-tile; never drained to 0 in the loop.
// =====================================================================
DEVINL void gemm256_core(const unsigned short* __restrict__ A,
                         const unsigned short* __restrict__ W,
                         char* lds, int tid, int wave, int lane,
                         int bm, int bn, f32x4 (&acc)[8][4]) {
  const char* Ag = (const char*)A;
  const char* Wg = (const char*)W;
  const int Ah = wave >> 2;        // which A half this wave computes (0/1)
  const int wn = (wave & 3) * 64;  // wave's B col offset
  const int lrow = lane & 15;
  const int lgrp = lane >> 4;      // 0..3

  auto stage = [&](int buf, int tk) {
#pragma unroll
    for (int hh = 0; hh < 4; ++hh) {
#pragma unroll
      for (int j = 0; j < 2; ++j) {
        const int lbyte = j * 8192 + tid * 16;       // linear LDS byte
        const int row = lbyte >> 7;                  // 128 B per row
        const int gcb = (lbyte & 127) ^ ((row & 7) << 4);  // inverse swizzle
        const char* src = (hh < 2)
            ? Ag + (size_t)(bm * 256 + hh * 128 + row) * 2048 + tk * 128 + gcb
            : Wg + (size_t)(bn * 256 + (hh - 2) * 128 + row) * 2048 + tk * 128 + gcb;
        char* dst = lds + buf * 65536 + (hh >= 2 ? 32768 : 0) + (hh & 1) * 16384 +
                    j * 8192 + wave * 1024;  // HW adds lane*16
        gload16(src, dst);
      }
    }
  };

  stage(0, 0);  // prologue: tile 0 into buf 0

  for (int t = 0; t < NT; ++t) {
    const int cur = t & 1;
    const char* Abase = lds + cur * 65536 + Ah * 16384;
    const char* Bbase = lds + cur * 65536 + 32768;

    // ---- phase 1: stage tile t+1, wait tile t resident, quad (mlo, nlo) ----
    stage(cur ^ 1, t + 1);
    asm volatile("s_waitcnt vmcnt(8)" ::: "memory");
    __builtin_amdgcn_sched_barrier(0);
    __builtin_amdgcn_s_barrier();
    __builtin_amdgcn_sched_barrier(0);

    bf16x8 aF[4][2], bF[4][2];
#pragma unroll
    for (int m = 0; m < 4; ++m)
#pragma unroll
      for (int ks = 0; ks < 2; ++ks) {
        const int r = m * 16 + lrow;
        const int cb = ks * 64 + lgrp * 16;
        aF[m][ks] = *(const bf16x8*)(Abase + r * 128 + (cb ^ ((r & 7) << 4)));
      }
#pragma unroll
    for (int n = 0; n < 2; ++n)
#pragma unroll
      for (int ks = 0; ks < 2; ++ks) {
        const int nr = wn + n * 16 + lrow;
        const int cb = ks * 64 + lgrp * 16;
        bF[n][ks] = *(const bf16x8*)(Bbase + nr * 128 + (cb ^ ((nr & 7) << 4)));
      }
    __builtin_amdgcn_s_setprio(1);
#pragma unroll
    for (int m = 0; m < 4; ++m)
#pragma unroll
      for (int n = 0; n < 2; ++n)
#pragma unroll
        for (int ks = 0; ks < 2; ++ks)
          acc[m][n] = __builtin_amdgcn_mfma_f32_16x16x32_bf16(aF[m][ks], bF[n][ks],
                                                              acc[m][n], 0, 0, 0);
    __builtin_amdgcn_s_setprio(0);
    __builtin_amdgcn_sched_barrier(0);
    __builtin_amdgcn_s_barrier();
    __builtin_amdgcn_sched_barrier(0);

    // ---- phase 2: load b n=2,3; quad (mlo, nhi) ----
#pragma unroll
    for (int n = 2; n < 4; ++n)
#pragma unroll
      for (int ks = 0; ks < 2; ++ks) {
        const int nr = wn + n * 16 + lrow;
        const int cb = ks * 64 + lgrp * 16;
        bF[n][ks] = *(const bf16x8*)(Bbase + nr * 128 + (cb ^ ((nr & 7) << 4)));
      }
    __builtin_amdgcn_s_setprio(1);
#pragma unroll
    for (int m = 0; m < 4; ++m)
#pragma unroll
      for (int n = 2; n < 4; ++n)
#pragma unroll
        for (int ks = 0; ks < 2; ++ks)
          acc[m][n] = __builtin_amdgcn_mfma_f32_16x16x32_bf16(aF[m][ks], bF[n][ks],
                                                              acc[m][n], 0, 0, 0);
    __builtin_amdgcn_s_setprio(0);
    __builtin_amdgcn_sched_barrier(0);
    __builtin_amdgcn_s_barrier();
    __builtin_amdgcn_sched_barrier(0);

    // ---- phase 3: load a m=4..7 (reuse regs); quad (mhi, nhi) ----
#pragma unroll
    for (int m = 0; m < 4; ++m)
#pragma unroll
      for (int ks = 0; ks < 2; ++ks) {
        const int r = (m + 4) * 16 + lrow;
        const int cb = ks * 64 + lgrp * 16;
        aF[m][ks] = *(const bf16x8*)(Abase + r * 128 + (cb ^ ((r & 7) << 4)));
      }
    __builtin_amdgcn_s_setprio(1);
#pragma unroll
    for (int m = 0; m < 4; ++m)
#pragma unroll
      for (int n = 2; n < 4; ++n)
#pragma unroll
        for (int ks = 0; ks < 2; ++ks)
          acc[m + 4][n] = __builtin_amdgcn_mfma_f32_16x16x32_bf16(aF[m][ks], bF[n][ks],
                                                                  acc[m + 4][n], 0, 0, 0);
    __builtin_amdgcn_s_setprio(0);
    __builtin_amdgcn_sched_barrier(0);
    __builtin_amdgcn_s_barrier();
    __builtin_amdgcn_sched_barrier(0);

    // ---- phase 4: no loads; quad (mhi, nlo); overlaps next phase-1 stage ----
    __builtin_amdgcn_s_setprio(1);
#pragma unroll
    for (int m = 0; m < 4; ++m)
#pragma unroll
      for (int n = 0; n < 2; ++n)
#pragma unroll
        for (int ks = 0; ks < 2; ++ks)
          acc[m + 4][n] = __builtin_amdgcn_mfma_f32_16x16x32_bf16(aF[m][ks], bF[n][ks],
                                                                  acc[m + 4][n], 0, 0, 0);
    __builtin_amdgcn_s_setprio(0);
    // no barrier: buf[cur] fully consumed after phase-3 barrier
  }
}

// ---------------- batched gate GEMM: z = {f, o, i_raw, z_raw} ----------------
struct GateArgs {
  const unsigned short* A[4];
  const unsigned short* W[4];
  const float* bias[4];
  unsigned short* out[4];
};

__global__ __launch_bounds__(512, 2) void gemm_gates8(GateArgs ga) {
  extern __shared__ char lds[];
  const int tid = threadIdx.x;
  const int wave = tid >> 6, lane = tid & 63;
  const int bm = blockIdx.x, bn = blockIdx.y, gz = blockIdx.z;
  const int wm = (wave >> 2) * 128, wn = (wave & 3) * 64;
  const int lrow = lane & 15, lgrp = lane >> 4;

  f32x4 acc[8][4];
#pragma unroll
  for (int m = 0; m < 8; ++m)
#pragma unroll
    for (int n = 0; n < 4; ++n) acc[m][n] = (f32x4){0.f, 0.f, 0.f, 0.f};

  gemm256_core(ga.A[gz], ga.W[gz], lds, tid, wave, lane, bm, bn, acc);

  const float* bias = ga.bias[gz];
  unsigned short* out = ga.out[gz];
  float bv[4];
#pragma unroll
  for (int n = 0; n < 4; ++n) bv[n] = bias[bn * 256 + wn + n * 16 + lrow];

#pragma unroll
  for (int m = 0; m < 8; ++m)
#pragma unroll
    for (int n = 0; n < 4; ++n) {
      const int gc = bn * 256 + wn + n * 16 + lrow;
#pragma unroll
      for (int j = 0; j < 4; ++j) {
        const int gr = bm * 256 + wm + m * 16 + lgrp * 4 + j;
        float v = acc[m][n][j] + bv[n];
        if (gz == 0) v = sigmoidf_(v + 1.0f);       // f gate
        else if (gz == 1) v = sigmoidf_(v);         // o gate
        // gz==2 (i) / gz==3 (z): raw pre-activation (bias included)
        out[(size_t)gr * GN + gc] = f2bf(v);
      }
    }
}

// ---------------- output projection: bf16 A (Hb), f32 out ----------------
__global__ __launch_bounds__(512, 2) void gemm_proj8(
    const unsigned short* __restrict__ A, const unsigned short* __restrict__ W,
    const float* __restrict__ bias, float* __restrict__ out) {
  extern __shared__ char lds[];
  const int tid = threadIdx.x;
  const int wave = tid >> 6, lane = tid & 63;
  const int bm = blockIdx.x, bn = blockIdx.y;
  const int wm = (wave >> 2) * 128, wn = (wave & 3) * 64;
  const int lrow = lane & 15, lgrp = lane >> 4;

  f32x4 acc[8][4];
#pragma unroll
  for (int m = 0; m < 8; ++m)
#pragma unroll
    for (int n = 0; n < 4; ++n) acc[m][n] = (f32x4){0.f, 0.f, 0.f, 0.f};

  gemm256_core(A, W, lds, tid, wave, lane, bm, bn, acc);

  float bv[4];
#pragma unroll
  for (int n = 0; n < 4; ++n) bv[n] = bias[bn * 256 + wn + n * 16 + lrow];

#pragma unroll
  for (int m = 0; m < 8; ++m)
#pragma unroll
    for (int n = 0; n < 4; ++n) {
      const int gc = bn * 256 + wn + n * 16 + lrow;
#pragma unroll
      for (int j = 0; j < 4; ++j) {
        const int gr = bm * 256 + wm + m * 16 + lgrp * 4 + j;
        out[(size_t)gr * GN + gc] = acc[m][n][j] + bv[n];
      }
    }
}

// ---------------- scan phase A: per-chunk (prod f, local c) ----------------
__global__ void scan_phaseA_kernel(const unsigned short* __restrict__ F,
                                   const unsigned short* __restrict__ Ip,
                                   const unsigned short* __restrict__ Zp,
                                   float* __restrict__ Pt, float* __restrict__ Ct) {
  int tid = blockIdx.x * blockDim.x + threadIdx.x;  // NCH * NCHUNK = 262144
  int ch = tid & (NCH - 1), chunk = tid >> 12;
  int b = ch >> 10, n = ch & 1023;
  size_t base = ((size_t)(b * 2048 + chunk * CHUNK)) * 1024 + n;
  float c = 0.f, P = 1.f;
#pragma unroll 8
  for (int t = 0; t < CHUNK; ++t) {
    size_t idx = base + (size_t)t * 1024;
    float f = bf2f(F[idx]);
    float u = sigmoidf_(bf2f(Ip[idx])) * tanhf(bf2f(Zp[idx]));
    c = __builtin_fmaf(f, c, u);
    P *= f;
  }
  Pt[tid] = P;
  Ct[tid] = c;
}

// ---------------- scan combine: sequential over 64 chunks ----------------
__global__ void scan_combine_kernel(const float* __restrict__ Pt,
                                    const float* __restrict__ Ct,
                                    const float* __restrict__ c0,
                                    float* __restrict__ Cin,
                                    float* __restrict__ last_c) {
  int ch = blockIdx.x * blockDim.x + threadIdx.x;  // 4096
  float c = c0[ch];
#pragma unroll
  for (int j = 0; j < NCHUNK; ++j) {
    Cin[j * NCH + ch] = c;
    c = __builtin_fmaf(Pt[j * NCH + ch], c, Ct[j * NCH + ch]);
  }
  last_c[ch] = c;
}

// ---------------- scan phase C: replay with carry, emit h ----------------
__global__ void scan_phaseC_kernel(const unsigned short* __restrict__ F,
                                   const unsigned short* __restrict__ Ip,
                                   const unsigned short* __restrict__ Zp,
                                   const unsigned short* __restrict__ O,
                                   const float* __restrict__ Cin,
                                   unsigned short* __restrict__ Hb,
                                   float* __restrict__ last_h) {
  int tid = blockIdx.x * blockDim.x + threadIdx.x;
  int ch = tid & (NCH - 1), chunk = tid >> 12;
  int b = ch >> 10, n = ch & 1023;
  size_t base = ((size_t)(b * 2048 + chunk * CHUNK)) * 1024 + n;
  float c = Cin[tid];  // tid == chunk*NCH + ch
  float h = 0.f;
#pragma unroll 8
  for (int t = 0; t < CHUNK; ++t) {
    size_t idx = base + (size_t)t * 1024;
    float f = bf2f(F[idx]);
    float u = sigmoidf_(bf2f(Ip[idx])) * tanhf(bf2f(Zp[idx]));
    float o = bf2f(O[idx]);
    c = __builtin_fmaf(f, c, u);
    h = o * tanhf(c);
    Hb[idx] = f2bf(h);
  }
  if (chunk == NCHUNK - 1) last_h[ch] = h;
}

extern "C" void kernel_launch(void* const* d_in, const int* in_sizes, int n_in,
                              void* d_out, int out_size, void* d_ws, size_t ws_size,
                              hipStream_t stream) {
  const float* f_in = (const float*)d_in[0];
  const float* i_in = (const float*)d_in[1];
  const float* z_in = (const float*)d_in[2];
  const float* o_in = (const float*)d_in[3];
  const float* c0 = (const float*)d_in[4];
  // d_in[5] = h0 (unused by reference)
  const float* Wf = (const float*)d_in[6];
  const float* bf_ = (const float*)d_in[7];
  const float* Wi = (const float*)d_in[8];
  const float* bi = (const float*)d_in[9];
  const float* Wz = (const float*)d_in[10];
  const float* bz = (const float*)d_in[11];
  const float* Wo = (const float*)d_in[12];
  const float* bo = (const float*)d_in[13];
  const float* Wp = (const float*)d_in[14];
  const float* bp = (const float*)d_in[15];

  float* y = (float*)d_out;
  float* last_c = y + NACT;
  float* last_h = last_c + NCH;

  // workspace carve (141 MB total; Hb aliases Af, which is dead after gate GEMMs)
  char* w = (char*)d_ws;
  const size_t ABYTES = NACT * 2;             // 16 MiB
  const size_t WBYTES = (size_t)GK * GN * 2;  // 2 MiB
  unsigned short* Af = (unsigned short*)(w + 0 * ABYTES);
  unsigned short* Ai = (unsigned short*)(w + 1 * ABYTES);
  unsigned short* Az = (unsigned short*)(w + 2 * ABYTES);
  unsigned short* Ao = (unsigned short*)(w + 3 * ABYTES);
  char* wt = w + 4 * ABYTES;
  unsigned short* Wtf = (unsigned short*)(wt + 0 * WBYTES);
  unsigned short* Wti = (unsigned short*)(wt + 1 * WBYTES);
  unsigned short* Wtz = (unsigned short*)(wt + 2 * WBYTES);
  unsigned short* Wto = (unsigned short*)(wt + 3 * WBYTES);
  unsigned short* Wtp = (unsigned short*)(wt + 4 * WBYTES);
  char* gp = wt + 5 * WBYTES;
  unsigned short* F = (unsigned short*)(gp + 0 * ABYTES);
  unsigned short* O = (unsigned short*)(gp + 1 * ABYTES);
  unsigned short* Ip = (unsigned short*)(gp + 2 * ABYTES);
  unsigned short* Zp = (unsigned short*)(gp + 3 * ABYTES);
  unsigned short* Hb = Af;  // alias: Af no longer needed after gate GEMMs
  char* sp = gp + 4 * ABYTES;
  const size_t SBYTES = (size_t)NCH * NCHUNK * 4;  // 1 MiB
  float* Pt = (float*)(sp + 0 * SBYTES);
  float* Ct = (float*)(sp + 1 * SBYTES);
  float* Cin = (float*)(sp + 2 * SBYTES);

  // allow 128 KiB dynamic LDS for the GEMM kernels (idempotent, capture-safe)
  (void)hipFuncSetAttribute((const void*)gemm_gates8,
                            hipFuncAttributeMaxDynamicSharedMemorySize, 131072);
  (void)hipFuncSetAttribute((const void*)gemm_proj8,
                            hipFuncAttributeMaxDynamicSharedMemorySize, 131072);

  // 1) convert activations f32 -> bf16 (one dispatch)
  cvt4_kernel<<<dim3(1024, 4), 256, 0, stream>>>(
      f_in, o_in, i_in, z_in, Af, Ao, Ai, Az, (int)(NACT / 4));

  // 2) transpose+convert weights -> Wt[n][k] bf16 (one dispatch)
  TPtrs tp;
  tp.src[0] = Wf; tp.src[1] = Wi; tp.src[2] = Wz; tp.src[3] = Wo; tp.src[4] = Wp;
  tp.dst[0] = Wtf; tp.dst[1] = Wti; tp.dst[2] = Wtz; tp.dst[3] = Wto; tp.dst[4] = Wtp;
  transpose_cvt_all<<<dim3(32, 32, 5), 256, 0, stream>>>(tp);

  // 3) all 4 gate GEMMs in one dispatch (512 blocks = 2 full CU rounds)
  GateArgs ga;
  ga.A[0] = Af;  ga.A[1] = Ao;  ga.A[2] = Ai;  ga.A[3] = Az;
  ga.W[0] = Wtf; ga.W[1] = Wto; ga.W[2] = Wti; ga.W[3] = Wtz;
  ga.bias[0] = bf_; ga.bias[1] = bo; ga.bias[2] = bi; ga.bias[3] = bz;
  ga.out[0] = F; ga.out[1] = O; ga.out[2] = Ip; ga.out[3] = Zp;
  gemm_gates8<<<dim3(GM / 256, GN / 256, 4), 512, 131072, stream>>>(ga);

  // 4) chunked linear-recurrence scan (u = sigmoid(ip)*tanh(zp) computed in-scan)
  scan_phaseA_kernel<<<(NCH * NCHUNK) / 256, 256, 0, stream>>>(F, Ip, Zp, Pt, Ct);
  scan_combine_kernel<<<NCH / 256, 256, 0, stream>>>(Pt, Ct, c0, Cin, last_c);
  scan_phaseC_kernel<<<(NCH * NCHUNK) / 256, 256, 0, stream>>>(F, Ip, Zp, O, Cin, Hb,
                                                               last_h);

  // 5) output projection
  gemm_proj8<<<dim3(GM / 256, GN / 256), 512, 131072, stream>>>(Hb, Wtp, bp, y);
}

// Round 4
// 206.150 us; speedup vs baseline: 1.2191x; 1.0535x over previous
//
#include <hip/hip_runtime.h>
#include <hip/hip_bf16.h>
#include <stdint.h>

// B=4, S=2048, HDIM=1024, H=16, D=64, L=128, NB=16
// GEMMs: M = B*S = 8192, N = H*D = 1024, K = HDIM = 1024
constexpr int GM = 8192;
constexpr int GK = 1024;
constexpr int GN = 1024;
constexpr size_t NACT = (size_t)GM * GN;      // 8388608 elements
constexpr int CHUNK = 32;                      // scan chunk length
constexpr int NCHUNK = 64;                     // 64*32 = 2048 = S
constexpr int NCH = 4096;                      // B*H*D channels
constexpr int NT = GK / 64;                    // 16 K-tiles of 64

#define DEVINL __device__ __forceinline__

typedef __attribute__((ext_vector_type(8))) short bf16x8;
typedef __attribute__((ext_vector_type(4))) float f32x4;

DEVINL float sigmoidf_(float x) { return 1.0f / (1.0f + __expf(-x)); }

DEVINL unsigned short f2bf(float x) {
  unsigned int u = __builtin_bit_cast(unsigned int, x);
  unsigned int rnd = 0x7fffu + ((u >> 16) & 1u);
  return (unsigned short)((u + rnd) >> 16);
}
DEVINL float bf2f(unsigned short u) {
  unsigned int x = ((unsigned int)u) << 16;
  return __builtin_bit_cast(float, x);
}

DEVINL void gload16(const void* g, void* l) {
  __builtin_amdgcn_global_load_lds(
      (const __attribute__((address_space(1))) unsigned int*)g,
      (__attribute__((address_space(3))) unsigned int*)l, 16, 0, 0);
}

// ---------------- prep: f32 -> bf16 convert, 4 arrays in one dispatch ----------------
__global__ void cvt4_kernel(const float* __restrict__ s0, const float* __restrict__ s1,
                            const float* __restrict__ s2, const float* __restrict__ s3,
                            unsigned short* __restrict__ d0, unsigned short* __restrict__ d1,
                            unsigned short* __restrict__ d2, unsigned short* __restrict__ d3,
                            int n4) {
  const float* s;
  unsigned short* d;
  switch (blockIdx.y) {
    case 0: s = s0; d = d0; break;
    case 1: s = s1; d = d1; break;
    case 2: s = s2; d = d2; break;
    default: s = s3; d = d3; break;
  }
  int stride = gridDim.x * blockDim.x;
  for (int i = blockIdx.x * blockDim.x + threadIdx.x; i < n4; i += stride) {
    float4 v = ((const float4*)s)[i];
    ushort4 o;
    o.x = f2bf(v.x); o.y = f2bf(v.y); o.z = f2bf(v.z); o.w = f2bf(v.w);
    ((ushort4*)d)[i] = o;
  }
}

// ---------------- prep: transpose+cvt all 5 weights in one dispatch ----------------
struct TPtrs {
  const float* src[5];
  unsigned short* dst[5];
};

__global__ void transpose_cvt_all(TPtrs p) {
  const float* __restrict__ W = p.src[blockIdx.z];
  unsigned short* __restrict__ Wt = p.dst[blockIdx.z];
  __shared__ float tile[32][33];
  int n0 = blockIdx.x * 32, k0 = blockIdx.y * 32;
  int tx = threadIdx.x & 31, ty = threadIdx.x >> 5;  // 32x8
#pragma unroll
  for (int i = 0; i < 32; i += 8)
    tile[ty + i][tx] = W[(size_t)(k0 + ty + i) * GN + n0 + tx];
  __syncthreads();
#pragma unroll
  for (int i = 0; i < 32; i += 8)
    Wt[(size_t)(n0 + ty + i) * GK + k0 + tx] = f2bf(tile[tx][ty + i]);
}

// =====================================================================
// 256x256 tile, BK=64, 8 waves (2M x 4N), m201-style 4-phase schedule:
//  P1: stage A(t+1) 4 gloads; vmcnt(4); barrier; read q1; MFMA (mlo,nlo)
//  P2: read bF-hi (pre-barrier); stage B(t+1); barrier; lgkm0; MFMA (mlo,nhi)
//  P3: read aF-hi (pre-barrier); barrier; lgkm0; MFMA (mhi,nhi)
//  P4: barrier; MFMA (mhi,nlo)   -- no loads; overlaps next P1 stage
// LDS 128 KiB: 2 dbuf x (A 32K + B 32K), linear dest + inverse-XOR-swizzled
// global source; reads apply the same XOR involution: cb ^= (row&7)<<4.
// Counted vmcnt only; never drained to 0 in the main loop.
// =====================================================================
DEVINL void gemm256_core(const unsigned short* __restrict__ A,
                         const unsigned short* __restrict__ W,
                         char* lds, int tid, int wave, int lane,
                         int bm, int bn, f32x4 (&acc)[8][4]) {
  const int Ah = wave >> 2;        // A half this wave computes (0/1)
  const int wn = (wave & 3) * 64;  // wave's B col offset
  const int lrow = lane & 15;
  const int lgrp = lane >> 4;      // 0..3

  // precompute the 8 per-thread staging (src, dst) pairs; src advances 128 B/tile
  const char* gsrc[8];
  char* ldst[8];
  {
    const char* Ag = (const char*)A;
    const char* Wg = (const char*)W;
#pragma unroll
    for (int hh = 0; hh < 4; ++hh)
#pragma unroll
      for (int j = 0; j < 2; ++j) {
        const int lbyte = j * 8192 + tid * 16;             // linear LDS byte
        const int row = lbyte >> 7;                        // 128 B per row
        const int gcb = (lbyte & 127) ^ ((row & 7) << 4);  // inverse swizzle
        const int i = hh * 2 + j;
        gsrc[i] = (hh < 2)
            ? Ag + (size_t)(bm * 256 + hh * 128 + row) * 2048 + gcb
            : Wg + (size_t)(bn * 256 + (hh - 2) * 128 + row) * 2048 + gcb;
        ldst[i] = lds + (hh >= 2 ? 32768 : 0) + (hh & 1) * 16384 + j * 8192 +
                  wave * 1024;  // HW adds lane*16
      }
  }

  // prologue: tile 0 -> buf 0 (all 8)
#pragma unroll
  for (int i = 0; i < 8; ++i) gload16(gsrc[i], ldst[i]);

  bf16x8 aF[4][2], bF[4][2];

  for (int t = 0; t < NT; ++t) {
    const int cur = t & 1;
    const int obuf = (cur ^ 1) * 65536;
    const char* Abase = lds + cur * 65536 + Ah * 16384;
    const char* Bbase = lds + cur * 65536 + 32768;
    const int nk = (t + 1 < NT) ? (t + 1) : (NT - 1);  // clamped dummy on last tile
    const size_t koff = (size_t)nk * 128;

    // ---- P1: stage A(t+1); counted wait for tile t; read q1; MFMA (mlo,nlo) ----
#pragma unroll
    for (int i = 0; i < 4; ++i) gload16(gsrc[i] + koff, ldst[i] + obuf);
    asm volatile("s_waitcnt vmcnt(4)" ::: "memory");
    __builtin_amdgcn_s_barrier();
    __builtin_amdgcn_sched_barrier(0);
#pragma unroll
    for (int m = 0; m < 4; ++m)
#pragma unroll
      for (int ks = 0; ks < 2; ++ks) {
        const int r = m * 16 + lrow;
        const int cb = ks * 64 + lgrp * 16;
        aF[m][ks] = *(const bf16x8*)(Abase + r * 128 + (cb ^ ((r & 7) << 4)));
      }
#pragma unroll
    for (int n = 0; n < 2; ++n)
#pragma unroll
      for (int ks = 0; ks < 2; ++ks) {
        const int nr = wn + n * 16 + lrow;
        const int cb = ks * 64 + lgrp * 16;
        bF[n][ks] = *(const bf16x8*)(Bbase + nr * 128 + (cb ^ ((nr & 7) << 4)));
      }
    __builtin_amdgcn_s_setprio(1);
#pragma unroll
    for (int m = 0; m < 4; ++m)
#pragma unroll
      for (int n = 0; n < 2; ++n)
#pragma unroll
        for (int ks = 0; ks < 2; ++ks)
          acc[m][n] = __builtin_amdgcn_mfma_f32_16x16x32_bf16(aF[m][ks], bF[n][ks],
                                                              acc[m][n], 0, 0, 0);
    __builtin_amdgcn_s_setprio(0);

    // ---- P2: read bF-hi pre-barrier; stage B(t+1); barrier; lgkm0; MFMA (mlo,nhi) ----
#pragma unroll
    for (int n = 2; n < 4; ++n)
#pragma unroll
      for (int ks = 0; ks < 2; ++ks) {
        const int nr = wn + n * 16 + lrow;
        const int cb = ks * 64 + lgrp * 16;
        bF[n][ks] = *(const bf16x8*)(Bbase + nr * 128 + (cb ^ ((nr & 7) << 4)));
      }
#pragma unroll
    for (int i = 4; i < 8; ++i) gload16(gsrc[i] + koff, ldst[i] + obuf);
    __builtin_amdgcn_s_barrier();
    asm volatile("s_waitcnt lgkmcnt(0)" ::: "memory");
    __builtin_amdgcn_sched_barrier(0);
    __builtin_amdgcn_s_setprio(1);
#pragma unroll
    for (int m = 0; m < 4; ++m)
#pragma unroll
      for (int n = 2; n < 4; ++n)
#pragma unroll
        for (int ks = 0; ks < 2; ++ks)
          acc[m][n] = __builtin_amdgcn_mfma_f32_16x16x32_bf16(aF[m][ks], bF[n][ks],
                                                              acc[m][n], 0, 0, 0);
    __builtin_amdgcn_s_setprio(0);

    // ---- P3: read aF-hi pre-barrier; barrier; lgkm0; MFMA (mhi,nhi) ----
#pragma unroll
    for (int m = 0; m < 4; ++m)
#pragma unroll
      for (int ks = 0; ks < 2; ++ks) {
        const int r = (m + 4) * 16 + lrow;
        const int cb = ks * 64 + lgrp * 16;
        aF[m][ks] = *(const bf16x8*)(Abase + r * 128 + (cb ^ ((r & 7) << 4)));
      }
    __builtin_amdgcn_s_barrier();
    asm volatile("s_waitcnt lgkmcnt(0)" ::: "memory");
    __builtin_amdgcn_sched_barrier(0);
    __builtin_amdgcn_s_setprio(1);
#pragma unroll
    for (int m = 0; m < 4; ++m)
#pragma unroll
      for (int n = 2; n < 4; ++n)
#pragma unroll
        for (int ks = 0; ks < 2; ++ks)
          acc[m + 4][n] = __builtin_amdgcn_mfma_f32_16x16x32_bf16(aF[m][ks], bF[n][ks],
                                                                  acc[m + 4][n], 0, 0, 0);
    __builtin_amdgcn_s_setprio(0);

    // ---- P4: barrier; MFMA (mhi,nlo) -- no loads; overlaps next P1 stage ----
    __builtin_amdgcn_s_barrier();
    __builtin_amdgcn_s_setprio(1);
#pragma unroll
    for (int m = 0; m < 4; ++m)
#pragma unroll
      for (int n = 0; n < 2; ++n)
#pragma unroll
        for (int ks = 0; ks < 2; ++ks)
          acc[m + 4][n] = __builtin_amdgcn_mfma_f32_16x16x32_bf16(aF[m][ks], bF[n][ks],
                                                                  acc[m + 4][n], 0, 0, 0);
    __builtin_amdgcn_s_setprio(0);
  }
}

// ---------------- batched gate GEMM: z = {f, o, i_raw, z_raw} ----------------
struct GateArgs {
  const unsigned short* A[4];
  const unsigned short* W[4];
  const float* bias[4];
  unsigned short* out[4];
};

__global__ __launch_bounds__(512, 2) void gemm_gates8(GateArgs ga) {
  extern __shared__ char lds[];
  const int tid = threadIdx.x;
  const int wave = tid >> 6, lane = tid & 63;
  const int bm = blockIdx.x, bn = blockIdx.y, gz = blockIdx.z;
  const int wm = (wave >> 2) * 128, wn = (wave & 3) * 64;
  const int lrow = lane & 15, lgrp = lane >> 4;

  f32x4 acc[8][4];
#pragma unroll
  for (int m = 0; m < 8; ++m)
#pragma unroll
    for (int n = 0; n < 4; ++n) acc[m][n] = (f32x4){0.f, 0.f, 0.f, 0.f};

  gemm256_core(ga.A[gz], ga.W[gz], lds, tid, wave, lane, bm, bn, acc);

  const float* bias = ga.bias[gz];
  unsigned short* out = ga.out[gz];
  float bv[4];
#pragma unroll
  for (int n = 0; n < 4; ++n) bv[n] = bias[bn * 256 + wn + n * 16 + lrow];

#pragma unroll
  for (int m = 0; m < 8; ++m)
#pragma unroll
    for (int n = 0; n < 4; ++n) {
      const int gc = bn * 256 + wn + n * 16 + lrow;
#pragma unroll
      for (int j = 0; j < 4; ++j) {
        const int gr = bm * 256 + wm + m * 16 + lgrp * 4 + j;
        float v = acc[m][n][j] + bv[n];
        if (gz == 0) v = sigmoidf_(v + 1.0f);       // f gate
        else if (gz == 1) v = sigmoidf_(v);         // o gate
        // gz==2 (i) / gz==3 (z): raw pre-activation (bias included)
        out[(size_t)gr * GN + gc] = f2bf(v);
      }
    }
}

// ---------------- output projection: bf16 A (Hb), f32 out ----------------
__global__ __launch_bounds__(512, 2) void gemm_proj8(
    const unsigned short* __restrict__ A, const unsigned short* __restrict__ W,
    const float* __restrict__ bias, float* __restrict__ out) {
  extern __shared__ char lds[];
  const int tid = threadIdx.x;
  const int wave = tid >> 6, lane = tid & 63;
  const int bm = blockIdx.x, bn = blockIdx.y;
  const int wm = (wave >> 2) * 128, wn = (wave & 3) * 64;
  const int lrow = lane & 15, lgrp = lane >> 4;

  f32x4 acc[8][4];
#pragma unroll
  for (int m = 0; m < 8; ++m)
#pragma unroll
    for (int n = 0; n < 4; ++n) acc[m][n] = (f32x4){0.f, 0.f, 0.f, 0.f};

  gemm256_core(A, W, lds, tid, wave, lane, bm, bn, acc);

  float bv[4];
#pragma unroll
  for (int n = 0; n < 4; ++n) bv[n] = bias[bn * 256 + wn + n * 16 + lrow];

#pragma unroll
  for (int m = 0; m < 8; ++m)
#pragma unroll
    for (int n = 0; n < 4; ++n) {
      const int gc = bn * 256 + wn + n * 16 + lrow;
#pragma unroll
      for (int j = 0; j < 4; ++j) {
        const int gr = bm * 256 + wm + m * 16 + lgrp * 4 + j;
        out[(size_t)gr * GN + gc] = acc[m][n][j] + bv[n];
      }
    }
}

// ---------------- scan phase A: per-chunk (prod f, local c) ----------------
__global__ void scan_phaseA_kernel(const unsigned short* __restrict__ F,
                                   const unsigned short* __restrict__ Ip,
                                   const unsigned short* __restrict__ Zp,
                                   float* __restrict__ Pt, float* __restrict__ Ct) {
  int tid = blockIdx.x * blockDim.x + threadIdx.x;  // NCH * NCHUNK = 262144
  int ch = tid & (NCH - 1), chunk = tid >> 12;
  int b = ch >> 10, n = ch & 1023;
  size_t base = ((size_t)(b * 2048 + chunk * CHUNK)) * 1024 + n;
  float c = 0.f, P = 1.f;
#pragma unroll 8
  for (int t = 0; t < CHUNK; ++t) {
    size_t idx = base + (size_t)t * 1024;
    float f = bf2f(F[idx]);
    float u = sigmoidf_(bf2f(Ip[idx])) * tanhf(bf2f(Zp[idx]));
    c = __builtin_fmaf(f, c, u);
    P *= f;
  }
  Pt[tid] = P;
  Ct[tid] = c;
}

// ---------------- scan combine: sequential over 64 chunks ----------------
__global__ void scan_combine_kernel(const float* __restrict__ Pt,
                                    const float* __restrict__ Ct,
                                    const float* __restrict__ c0,
                                    float* __restrict__ Cin,
                                    float* __restrict__ last_c) {
  int ch = blockIdx.x * blockDim.x + threadIdx.x;  // 4096
  float c = c0[ch];
#pragma unroll
  for (int j = 0; j < NCHUNK; ++j) {
    Cin[j * NCH + ch] = c;
    c = __builtin_fmaf(Pt[j * NCH + ch], c, Ct[j * NCH + ch]);
  }
  last_c[ch] = c;
}

// ---------------- scan phase C: replay with carry, emit h ----------------
__global__ void scan_phaseC_kernel(const unsigned short* __restrict__ F,
                                   const unsigned short* __restrict__ Ip,
                                   const unsigned short* __restrict__ Zp,
                                   const unsigned short* __restrict__ O,
                                   const float* __restrict__ Cin,
                                   unsigned short* __restrict__ Hb,
                                   float* __restrict__ last_h) {
  int tid = blockIdx.x * blockDim.x + threadIdx.x;
  int ch = tid & (NCH - 1), chunk = tid >> 12;
  int b = ch >> 10, n = ch & 1023;
  size_t base = ((size_t)(b * 2048 + chunk * CHUNK)) * 1024 + n;
  float c = Cin[tid];  // tid == chunk*NCH + ch
  float h = 0.f;
#pragma unroll 8
  for (int t = 0; t < CHUNK; ++t) {
    size_t idx = base + (size_t)t * 1024;
    float f = bf2f(F[idx]);
    float u = sigmoidf_(bf2f(Ip[idx])) * tanhf(bf2f(Zp[idx]));
    float o = bf2f(O[idx]);
    c = __builtin_fmaf(f, c, u);
    h = o * tanhf(c);
    Hb[idx] = f2bf(h);
  }
  if (chunk == NCHUNK - 1) last_h[ch] = h;
}

extern "C" void kernel_launch(void* const* d_in, const int* in_sizes, int n_in,
                              void* d_out, int out_size, void* d_ws, size_t ws_size,
                              hipStream_t stream) {
  const float* f_in = (const float*)d_in[0];
  const float* i_in = (const float*)d_in[1];
  const float* z_in = (const float*)d_in[2];
  const float* o_in = (const float*)d_in[3];
  const float* c0 = (const float*)d_in[4];
  // d_in[5] = h0 (unused by reference)
  const float* Wf = (const float*)d_in[6];
  const float* bf_ = (const float*)d_in[7];
  const float* Wi = (const float*)d_in[8];
  const float* bi = (const float*)d_in[9];
  const float* Wz = (const float*)d_in[10];
  const float* bz = (const float*)d_in[11];
  const float* Wo = (const float*)d_in[12];
  const float* bo = (const float*)d_in[13];
  const float* Wp = (const float*)d_in[14];
  const float* bp = (const float*)d_in[15];

  float* y = (float*)d_out;
  float* last_c = y + NACT;
  float* last_h = last_c + NCH;

  // workspace carve (Hb aliases Af, which is dead after gate GEMMs)
  char* w = (char*)d_ws;
  const size_t ABYTES = NACT * 2;             // 16 MiB
  const size_t WBYTES = (size_t)GK * GN * 2;  // 2 MiB
  unsigned short* Af = (unsigned short*)(w + 0 * ABYTES);
  unsigned short* Ai = (unsigned short*)(w + 1 * ABYTES);
  unsigned short* Az = (unsigned short*)(w + 2 * ABYTES);
  unsigned short* Ao = (unsigned short*)(w + 3 * ABYTES);
  char* wt = w + 4 * ABYTES;
  unsigned short* Wtf = (unsigned short*)(wt + 0 * WBYTES);
  unsigned short* Wti = (unsigned short*)(wt + 1 * WBYTES);
  unsigned short* Wtz = (unsigned short*)(wt + 2 * WBYTES);
  unsigned short* Wto = (unsigned short*)(wt + 3 * WBYTES);
  unsigned short* Wtp = (unsigned short*)(wt + 4 * WBYTES);
  char* gp = wt + 5 * WBYTES;
  unsigned short* F = (unsigned short*)(gp + 0 * ABYTES);
  unsigned short* O = (unsigned short*)(gp + 1 * ABYTES);
  unsigned short* Ip = (unsigned short*)(gp + 2 * ABYTES);
  unsigned short* Zp = (unsigned short*)(gp + 3 * ABYTES);
  unsigned short* Hb = Af;  // alias: Af no longer needed after gate GEMMs
  char* sp = gp + 4 * ABYTES;
  const size_t SBYTES = (size_t)NCH * NCHUNK * 4;  // 1 MiB
  float* Pt = (float*)(sp + 0 * SBYTES);
  float* Ct = (float*)(sp + 1 * SBYTES);
  float* Cin = (float*)(sp + 2 * SBYTES);

  // allow 128 KiB dynamic LDS for the GEMM kernels (idempotent, capture-safe)
  (void)hipFuncSetAttribute((const void*)gemm_gates8,
                            hipFuncAttributeMaxDynamicSharedMemorySize, 131072);
  (void)hipFuncSetAttribute((const void*)gemm_proj8,
                            hipFuncAttributeMaxDynamicSharedMemorySize, 131072);

  // 1) convert activations f32 -> bf16 (one dispatch)
  cvt4_kernel<<<dim3(1024, 4), 256, 0, stream>>>(
      f_in, o_in, i_in, z_in, Af, Ao, Ai, Az, (int)(NACT / 4));

  // 2) transpose+convert weights -> Wt[n][k] bf16 (one dispatch)
  TPtrs tp;
  tp.src[0] = Wf; tp.src[1] = Wi; tp.src[2] = Wz; tp.src[3] = Wo; tp.src[4] = Wp;
  tp.dst[0] = Wtf; tp.dst[1] = Wti; tp.dst[2] = Wtz; tp.dst[3] = Wto; tp.dst[4] = Wtp;
  transpose_cvt_all<<<dim3(32, 32, 5), 256, 0, stream>>>(tp);

  // 3) all 4 gate GEMMs in one dispatch (512 blocks = 2 full CU rounds)
  GateArgs ga;
  ga.A[0] = Af;  ga.A[1] = Ao;  ga.A[2] = Ai;  ga.A[3] = Az;
  ga.W[0] = Wtf; ga.W[1] = Wto; ga.W[2] = Wti; ga.W[3] = Wtz;
  ga.bias[0] = bf_; ga.bias[1] = bo; ga.bias[2] = bi; ga.bias[3] = bz;
  ga.out[0] = F; ga.out[1] = O; ga.out[2] = Ip; ga.out[3] = Zp;
  gemm_gates8<<<dim3(GM / 256, GN / 256, 4), 512, 131072, stream>>>(ga);

  // 4) chunked linear-recurrence scan (u = sigmoid(ip)*tanh(zp) computed in-scan)
  scan_phaseA_kernel<<<(NCH * NCHUNK) / 256, 256, 0, stream>>>(F, Ip, Zp, Pt, Ct);
  scan_combine_kernel<<<NCH / 256, 256, 0, stream>>>(Pt, Ct, c0, Cin, last_c);
  scan_phaseC_kernel<<<(NCH * NCHUNK) / 256, 256, 0, stream>>>(F, Ip, Zp, O, Cin, Hb,
                                                               last_h);

  // 5) output projection
  gemm_proj8<<<dim3(GM / 256, GN / 256), 512, 131072, stream>>>(Hb, Wtp, bp, y);
}